// Round 1
// baseline (458.964 us; speedup 1.0000x reference)
//
#include <hip/hip_runtime.h>
#include <math.h>

#define N_NODES 10000
#define E_EDGES 160000
#define IN_FEATS 128
#define DMODEL 64
#define H 4
#define NBOUND 31
#define HD (H * DMODEL)  // 256

// ---------------------------------------------------------------------------
// K0: precompute combined matrices.
//  For k in {0,1,2} (branches fc1/fc2/fc3), head h:
//    F_k[h]  = attn_fc[h][k*64:(k+1)*64, :]            (64x64)
//    B_k[h]  = attn_fc{k}[h] (128x64) @ F_k[h]         (128x64)
//    C_k[h]  = B_k[h][0:64]                            (64x64)  -> node path
//    U_k[h]  = embed(32x32) @ (G[h](32x64) @ B_k[h][64:128]) (32x64) -> dist path
// ---------------------------------------------------------------------------
__global__ __launch_bounds__(256) void precompute_kernel(
    const float* __restrict__ fc1, const float* __restrict__ fc2,
    const float* __restrict__ fc3, const float* __restrict__ fcc,
    const float* __restrict__ G, const float* __restrict__ emb,
    float* __restrict__ Cbuf, float* __restrict__ Ubuf) {
  __shared__ float Flds[64 * 64];
  __shared__ float Blds[128 * 64];
  __shared__ float GBlds[32 * 64];
  int k = blockIdx.x >> 2;
  int h = blockIdx.x & 3;
  const float* fck = (k == 0) ? fc1 : (k == 1) ? fc2 : fc3;
  fck += h * 128 * 64;
  const float* F = fcc + h * 192 * 64 + k * 64 * 64;  // rows k*64 .. k*64+63
  int tid = threadIdx.x;
  for (int x = tid; x < 64 * 64; x += 256) Flds[x] = F[x];
  __syncthreads();
  int j = tid & 63;
  int ig = tid >> 6;
  for (int ii = 0; ii < 32; ++ii) {
    int i = ig * 32 + ii;
    float acc = 0.f;
    #pragma unroll 8
    for (int t = 0; t < 64; ++t) acc += fck[i * 64 + t] * Flds[t * 64 + j];
    Blds[i * 64 + j] = acc;
    if (i < 64) Cbuf[k * 16384 + h * 4096 + i * 64 + j] = acc;
  }
  __syncthreads();
  for (int id = tid; id < 32 * 64; id += 256) {
    int g = id >> 6, jj = id & 63;
    float acc = 0.f;
    #pragma unroll 8
    for (int dd = 0; dd < 64; ++dd)
      acc += G[h * 2048 + g * 64 + dd] * Blds[(64 + dd) * 64 + jj];
    GBlds[id] = acc;
  }
  __syncthreads();
  for (int id = tid; id < 32 * 64; id += 256) {
    int ie = id >> 6, jj = id & 63;
    float acc = 0.f;
    #pragma unroll 8
    for (int g = 0; g < 32; ++g)
      acc += emb[ie * 32 + g] * GBlds[g * 64 + jj];
    Ubuf[k * 8192 + h * 2048 + id] = acc;
  }
}

// ---------------------------------------------------------------------------
// K1: per-node. h = feat @ W_fc  (N x 256), then q_k[n,h] = h[n,h] @ C_k[h].
// 8 nodes per block of 256 threads.
// ---------------------------------------------------------------------------
__global__ __launch_bounds__(256) void node_kernel(
    const float* __restrict__ feat, const float* __restrict__ Wfc,
    const float* __restrict__ Cbuf, float* __restrict__ hbuf,
    float* __restrict__ q1, float* __restrict__ q2, float* __restrict__ q3) {
  __shared__ float flds[8 * 128];
  __shared__ float hlds[8 * 256];
  int tid = threadIdx.x;
  int n0 = blockIdx.x * 8;
  for (int x = tid; x < 8 * 128; x += 256) flds[x] = feat[n0 * 128 + x];
  __syncthreads();
  float acc[8];
  #pragma unroll
  for (int r = 0; r < 8; ++r) acc[r] = 0.f;
  for (int kk = 0; kk < 128; ++kk) {
    float w = Wfc[kk * 256 + tid];
    #pragma unroll
    for (int r = 0; r < 8; ++r) acc[r] += flds[r * 128 + kk] * w;
  }
  #pragma unroll
  for (int r = 0; r < 8; ++r) {
    hlds[r * 256 + tid] = acc[r];
    hbuf[(n0 + r) * 256 + tid] = acc[r];
  }
  __syncthreads();
  int hh = tid >> 6, dd = tid & 63;
  float* qs[3] = {q1, q2, q3};
  for (int kq = 0; kq < 3; ++kq) {
    const float* C = Cbuf + kq * 16384 + hh * 4096;
    float a2[8];
    #pragma unroll
    for (int r = 0; r < 8; ++r) a2[r] = 0.f;
    for (int jj = 0; jj < 64; ++jj) {
      float c = C[jj * 64 + dd];
      #pragma unroll
      for (int r = 0; r < 8; ++r) a2[r] += hlds[r * 256 + hh * 64 + jj] * c;
    }
    float* q = qs[kq];
    #pragma unroll
    for (int r = 0; r < 8; ++r) q[(n0 + r) * 256 + tid] = a2[r];
  }
}

// ---------------------------------------------------------------------------
// CSR build
// ---------------------------------------------------------------------------
__global__ __launch_bounds__(256) void count_kernel(const int* __restrict__ dst,
                                                    int* __restrict__ counts) {
  int e = blockIdx.x * 256 + threadIdx.x;
  if (e < E_EDGES) atomicAdd(&counts[dst[e]], 1);
}

__global__ __launch_bounds__(1024) void scan_kernel(const int* __restrict__ counts,
                                                    int* __restrict__ starts,
                                                    int* __restrict__ cursor) {
  __shared__ int lds[1024];
  __shared__ int carry_s;
  int tid = threadIdx.x;
  if (tid == 0) carry_s = 0;
  __syncthreads();
  for (int base = 0; base < N_NODES; base += 1024) {
    int i = base + tid;
    int v = (i < N_NODES) ? counts[i] : 0;
    int x = v;
    lds[tid] = x;
    __syncthreads();
    for (int off = 1; off < 1024; off <<= 1) {
      int y = (tid >= off) ? lds[tid - off] : 0;
      __syncthreads();
      x += y;
      lds[tid] = x;
      __syncthreads();
    }
    int cbase = carry_s;
    int excl = cbase + x - v;
    if (i < N_NODES) {
      starts[i] = excl;
      cursor[i] = excl;
    }
    __syncthreads();
    if (tid == 0) carry_s = cbase + lds[1023];
    __syncthreads();
  }
  if (tid == 0) starts[N_NODES] = carry_s;
}

__global__ __launch_bounds__(256) void fill_kernel(const int* __restrict__ dst,
                                                   int* __restrict__ cursor,
                                                   int* __restrict__ elist) {
  int e = blockIdx.x * 256 + threadIdx.x;
  if (e < E_EDGES) {
    int p = atomicAdd(&cursor[dst[e]], 1);
    elist[p] = e;
  }
}

// ---------------------------------------------------------------------------
// K3: edge scores. One wave per edge (4 waves/block), lane = d.
// searchsorted(left) == count of boundaries < dist == lower_bound.
// ---------------------------------------------------------------------------
__device__ __forceinline__ int bsearch31(const float* __restrict__ bnd, float d) {
  int lo = 0, hi = NBOUND;  // bnd[31] = +inf pad
  #pragma unroll
  for (int it = 0; it < 5; ++it) {
    int mid = (lo + hi) >> 1;
    bool c = bnd[mid] < d;
    lo = c ? mid + 1 : lo;
    hi = c ? hi : mid;
  }
  return lo;
}

__global__ __launch_bounds__(256) void edge_kernel(
    const int* __restrict__ src, const int* __restrict__ dst,
    const int* __restrict__ inter, const float* __restrict__ pos,
    const float* __restrict__ boundaries, const float* __restrict__ q1,
    const float* __restrict__ q2, const float* __restrict__ q3,
    const float* __restrict__ U, const float* __restrict__ aout,
    float* __restrict__ escore) {
  __shared__ float bnd[32];
  if (threadIdx.x < NBOUND) bnd[threadIdx.x] = boundaries[threadIdx.x];
  if (threadIdx.x == NBOUND) bnd[NBOUND] = INFINITY;
  __syncthreads();
  int w = threadIdx.x >> 6;
  int lane = threadIdx.x & 63;
  int e = blockIdx.x * 4 + w;
  int s = src[e], t = dst[e];
  float sx = pos[s * 3 + 0], sy = pos[s * 3 + 1], sz = pos[s * 3 + 2];
  float tx = pos[t * 3 + 0], ty = pos[t * 3 + 1], tz = pos[t * 3 + 2];
  float dx = tx - sx, dy = ty - sy, dz = tz - sz;
  float dist1 = sqrtf(dx * dx + dy * dy + dz * dz);
  int idx1 = bsearch31(bnd, dist1);
  const float* U1 = U;
  const float* U2 = U + 8192;
  const float* U3 = U + 16384;
  #pragma unroll
  for (int h = 0; h < H; ++h) {
    int it = inter[e * H + h];
    float ix = pos[it * 3 + 0], iy = pos[it * 3 + 1], iz = pos[it * 3 + 2];
    float ax = tx - ix, ay = ty - iy, az = tz - iz;
    float dist2 = sqrtf(ax * ax + ay * ay + az * az);
    float bx = sx - ix, by = sy - iy, bz = sz - iz;
    float dist_ = sqrtf(bx * bx + by * by + bz * bz);
    int idx2 = bsearch31(bnd, dist2);
    int idx_ = bsearch31(bnd, dist_);
    float z = q1[(s * H + h) * 64 + lane] + q2[(it * H + h) * 64 + lane] +
              q3[(t * H + h) * 64 + lane] + U1[(h * 32 + idx1) * 64 + lane] +
              U2[(h * 32 + idx2) * 64 + lane] + U3[(h * 32 + idx_) * 64 + lane];
    float v = tanhf(z) * aout[h * 64 + lane];
    #pragma unroll
    for (int off = 32; off > 0; off >>= 1) v += __shfl_xor(v, off);
    if (lane == 0) escore[e * H + h] = v;
  }
}

// ---------------------------------------------------------------------------
// K4: per-node softmax + weighted aggregation + head mean.
// One block per node; wave = head; lane = d.
// ---------------------------------------------------------------------------
__global__ __launch_bounds__(256) void agg_kernel(
    const int* __restrict__ starts, const int* __restrict__ elist,
    const int* __restrict__ src, const float* __restrict__ escore,
    const float* __restrict__ hbuf, float* __restrict__ out) {
  __shared__ float red[H][64];
  int n = blockIdx.x;
  int h = threadIdx.x >> 6;
  int lane = threadIdx.x & 63;
  int b = starts[n], eend = starts[n + 1];
  float m = -INFINITY;
  for (int i = b + lane; i < eend; i += 64)
    m = fmaxf(m, escore[elist[i] * H + h]);
  #pragma unroll
  for (int off = 32; off > 0; off >>= 1) m = fmaxf(m, __shfl_xor(m, off));
  float den = 0.f, num = 0.f;
  for (int i = b; i < eend; ++i) {
    int e = elist[i];
    float ex = __expf(escore[e * H + h] - m);
    den += ex;
    num += ex * hbuf[(src[e] * H + h) * 64 + lane];
  }
  red[h][lane] = (eend > b) ? (num / den) : 0.f;
  __syncthreads();
  if (threadIdx.x < 64) {
    out[n * 64 + lane] =
        0.25f * (red[0][lane] + red[1][lane] + red[2][lane] + red[3][lane]);
  }
}

// ---------------------------------------------------------------------------
extern "C" void kernel_launch(void* const* d_in, const int* in_sizes, int n_in,
                              void* d_out, int out_size, void* d_ws,
                              size_t ws_size, hipStream_t stream) {
  const float* feat = (const float*)d_in[0];
  const float* loc = (const float*)d_in[1];
  const int* src = (const int*)d_in[2];
  const int* dst = (const int*)d_in[3];
  const int* inter = (const int*)d_in[4];
  const float* Wfc = (const float*)d_in[5];
  const float* emb = (const float*)d_in[6];
  const float* G = (const float*)d_in[7];
  const float* fc1 = (const float*)d_in[8];
  const float* fc2 = (const float*)d_in[9];
  const float* fc3 = (const float*)d_in[10];
  const float* fcc = (const float*)d_in[11];
  const float* aout = (const float*)d_in[12];
  const float* bnd = (const float*)d_in[13];
  float* out = (float*)d_out;

  // workspace carve (floats)
  float* ws = (float*)d_ws;
  float* hbuf = ws;                       // N*256 = 2,560,000
  float* q1 = hbuf + N_NODES * HD;        // 2,560,000
  float* q2 = q1 + N_NODES * HD;          // 2,560,000
  float* q3 = q2 + N_NODES * HD;          // 2,560,000
  float* Cbuf = q3 + N_NODES * HD;        // 3*4*4096 = 49,152
  float* Ubuf = Cbuf + 3 * H * 4096;      // 3*4*2048 = 24,576
  float* escore = Ubuf + 3 * H * 2048;    // E*H = 640,000
  int* counts = (int*)(escore + E_EDGES * H);  // N
  int* starts = counts + N_NODES;              // N+1
  int* cursor = starts + N_NODES + 1;          // N
  int* elist = cursor + N_NODES;               // E

  hipMemsetAsync(counts, 0, N_NODES * sizeof(int), stream);
  precompute_kernel<<<12, 256, 0, stream>>>(fc1, fc2, fc3, fcc, G, emb, Cbuf,
                                            Ubuf);
  node_kernel<<<N_NODES / 8, 256, 0, stream>>>(feat, Wfc, Cbuf, hbuf, q1, q2,
                                               q3);
  count_kernel<<<(E_EDGES + 255) / 256, 256, 0, stream>>>(dst, counts);
  scan_kernel<<<1, 1024, 0, stream>>>(counts, starts, cursor);
  fill_kernel<<<(E_EDGES + 255) / 256, 256, 0, stream>>>(dst, cursor, elist);
  edge_kernel<<<E_EDGES / 4, 256, 0, stream>>>(src, dst, inter, loc, bnd, q1,
                                               q2, q3, Ubuf, aout, escore);
  agg_kernel<<<N_NODES, 256, 0, stream>>>(starts, elist, src, escore, hbuf,
                                          out);
}

// Round 2
// 328.649 us; speedup vs baseline: 1.3965x; 1.3965x over previous
//
#include <hip/hip_runtime.h>
#include <math.h>

#define N_NODES 10000
#define E_EDGES 160000
#define IN_FEATS 128
#define DMODEL 64
#define H 4
#define NBOUND 31
#define HD (H * DMODEL)  // 256

// ---------------------------------------------------------------------------
// K0: precompute combined matrices.
//  For k in {0,1,2} (branches fc1/fc2/fc3), head h:
//    F_k[h]  = attn_fc[h][k*64:(k+1)*64, :]            (64x64)
//    B_k[h]  = attn_fc{k}[h] (128x64) @ F_k[h]         (128x64)
//    C_k[h]  = B_k[h][0:64]                            (64x64)  -> node path
//    U_k[h]  = embed(32x32) @ (G[h](32x64) @ B_k[h][64:128]) (32x64) -> dist
// ---------------------------------------------------------------------------
__global__ __launch_bounds__(256) void precompute_kernel(
    const float* __restrict__ fc1, const float* __restrict__ fc2,
    const float* __restrict__ fc3, const float* __restrict__ fcc,
    const float* __restrict__ G, const float* __restrict__ emb,
    float* __restrict__ Cbuf, float* __restrict__ Ubuf) {
  __shared__ float Flds[64 * 64];
  __shared__ float Blds[128 * 64];
  __shared__ float GBlds[32 * 64];
  int k = blockIdx.x >> 2;
  int h = blockIdx.x & 3;
  const float* fck = (k == 0) ? fc1 : (k == 1) ? fc2 : fc3;
  fck += h * 128 * 64;
  const float* F = fcc + h * 192 * 64 + k * 64 * 64;  // rows k*64 .. k*64+63
  int tid = threadIdx.x;
  for (int x = tid; x < 64 * 64; x += 256) Flds[x] = F[x];
  __syncthreads();
  int j = tid & 63;
  int ig = tid >> 6;
  for (int ii = 0; ii < 32; ++ii) {
    int i = ig * 32 + ii;
    float acc = 0.f;
    #pragma unroll 8
    for (int t = 0; t < 64; ++t) acc += fck[i * 64 + t] * Flds[t * 64 + j];
    Blds[i * 64 + j] = acc;
    if (i < 64) Cbuf[k * 16384 + h * 4096 + i * 64 + j] = acc;
  }
  __syncthreads();
  for (int id = tid; id < 32 * 64; id += 256) {
    int g = id >> 6, jj = id & 63;
    float acc = 0.f;
    #pragma unroll 8
    for (int dd = 0; dd < 64; ++dd)
      acc += G[h * 2048 + g * 64 + dd] * Blds[(64 + dd) * 64 + jj];
    GBlds[id] = acc;
  }
  __syncthreads();
  for (int id = tid; id < 32 * 64; id += 256) {
    int ie = id >> 6, jj = id & 63;
    float acc = 0.f;
    #pragma unroll 8
    for (int g = 0; g < 32; ++g)
      acc += emb[ie * 32 + g] * GBlds[g * 64 + jj];
    Ubuf[k * 8192 + h * 2048 + id] = acc;
  }
}

// ---------------------------------------------------------------------------
// K1: per-node. h = feat @ W_fc  (N x 256), then q_k[n,h] = h[n,h] @ C_k[h].
// 8 nodes per block of 256 threads.
// ---------------------------------------------------------------------------
__global__ __launch_bounds__(256) void node_kernel(
    const float* __restrict__ feat, const float* __restrict__ Wfc,
    const float* __restrict__ Cbuf, float* __restrict__ hbuf,
    float* __restrict__ q1, float* __restrict__ q2, float* __restrict__ q3) {
  __shared__ float flds[8 * 128];
  __shared__ float hlds[8 * 256];
  int tid = threadIdx.x;
  int n0 = blockIdx.x * 8;
  for (int x = tid; x < 8 * 128; x += 256) flds[x] = feat[n0 * 128 + x];
  __syncthreads();
  float acc[8];
  #pragma unroll
  for (int r = 0; r < 8; ++r) acc[r] = 0.f;
  for (int kk = 0; kk < 128; ++kk) {
    float w = Wfc[kk * 256 + tid];
    #pragma unroll
    for (int r = 0; r < 8; ++r) acc[r] += flds[r * 128 + kk] * w;
  }
  #pragma unroll
  for (int r = 0; r < 8; ++r) {
    hlds[r * 256 + tid] = acc[r];
    hbuf[(n0 + r) * 256 + tid] = acc[r];
  }
  __syncthreads();
  int hh = tid >> 6, dd = tid & 63;
  float* qs[3] = {q1, q2, q3};
  for (int kq = 0; kq < 3; ++kq) {
    const float* C = Cbuf + kq * 16384 + hh * 4096;
    float a2[8];
    #pragma unroll
    for (int r = 0; r < 8; ++r) a2[r] = 0.f;
    for (int jj = 0; jj < 64; ++jj) {
      float c = C[jj * 64 + dd];
      #pragma unroll
      for (int r = 0; r < 8; ++r) a2[r] += hlds[r * 256 + hh * 64 + jj] * c;
    }
    float* q = qs[kq];
    #pragma unroll
    for (int r = 0; r < 8; ++r) q[(n0 + r) * 256 + tid] = a2[r];
  }
}

// ---------------------------------------------------------------------------
// CSR build
// ---------------------------------------------------------------------------
__global__ __launch_bounds__(256) void count_kernel(const int* __restrict__ dst,
                                                    int* __restrict__ counts) {
  int e = blockIdx.x * 256 + threadIdx.x;
  if (e < E_EDGES) atomicAdd(&counts[dst[e]], 1);
}

// 1024 threads, 10 nodes per thread serial + one 1024-wide LDS scan.
__global__ __launch_bounds__(1024) void scan_kernel(const int* __restrict__ counts,
                                                    int* __restrict__ starts,
                                                    int* __restrict__ cursor) {
  __shared__ int lds[1024];
  int tid = threadIdx.x;
  int base = tid * 10;
  int loc[10];
  int s = 0;
  #pragma unroll
  for (int u = 0; u < 10; ++u) {
    int i = base + u;
    int v = (i < N_NODES) ? counts[i] : 0;
    loc[u] = s;
    s += v;
  }
  lds[tid] = s;
  __syncthreads();
  int inc = s;
  for (int off = 1; off < 1024; off <<= 1) {
    int y = (tid >= off) ? lds[tid - off] : 0;
    __syncthreads();
    inc += y;
    lds[tid] = inc;
    __syncthreads();
  }
  int excl = inc - s;
  #pragma unroll
  for (int u = 0; u < 10; ++u) {
    int i = base + u;
    if (i < N_NODES) {
      int v = excl + loc[u];
      starts[i] = v;
      cursor[i] = v;
    }
  }
  if (tid == 1023) starts[N_NODES] = inc;
}

__global__ __launch_bounds__(256) void fill_kernel(const int* __restrict__ dst,
                                                   int* __restrict__ cursor,
                                                   int* __restrict__ elist) {
  int e = blockIdx.x * 256 + threadIdx.x;
  if (e < E_EDGES) {
    int p = atomicAdd(&cursor[dst[e]], 1);
    elist[p] = e;
  }
}

// ---------------------------------------------------------------------------
// K3: edge scores. One wave per EDGE; 16 lanes per head; each lane owns 4
// consecutive d-elements (float4 gathers). searchsorted(left) == lower_bound.
// ---------------------------------------------------------------------------
__device__ __forceinline__ int bsearch31(const float* __restrict__ bnd, float d) {
  int lo = 0, hi = NBOUND;  // bnd[31] = +inf pad
  #pragma unroll
  for (int it = 0; it < 5; ++it) {
    int mid = (lo + hi) >> 1;
    bool c = bnd[mid] < d;
    lo = c ? mid + 1 : lo;
    hi = c ? hi : mid;
  }
  return lo;
}

// branchless tanh: copysign(1 - 2/(e^{2|z|}+1), z); e^inf -> 2/inf = 0 -> 1.
__device__ __forceinline__ float fast_tanh(float z) {
  float a = fabsf(z);
  float p = __expf(2.0f * a);
  float r = 1.0f - 2.0f / (p + 1.0f);
  return copysignf(r, z);
}

__global__ __launch_bounds__(256) void edge_kernel(
    const int* __restrict__ src, const int* __restrict__ dst,
    const int* __restrict__ inter, const float* __restrict__ pos,
    const float* __restrict__ boundaries, const float* __restrict__ q1,
    const float* __restrict__ q2, const float* __restrict__ q3,
    const float* __restrict__ U, const float* __restrict__ aout,
    float* __restrict__ escore) {
  __shared__ float bnd[32];
  int tid = threadIdx.x;
  if (tid < NBOUND) bnd[tid] = boundaries[tid];
  if (tid == NBOUND) bnd[NBOUND] = INFINITY;
  __syncthreads();
  int w = tid >> 6;
  int lane = tid & 63;
  int h = lane >> 4;   // head
  int c = lane & 15;   // chunk: elements 4c..4c+3
  int e = blockIdx.x * 4 + w;
  int s = src[e], t = dst[e];
  int it = inter[e * H + h];
  float sx = pos[s * 3], sy = pos[s * 3 + 1], sz = pos[s * 3 + 2];
  float tx = pos[t * 3], ty = pos[t * 3 + 1], tz = pos[t * 3 + 2];
  float ix = pos[it * 3], iy = pos[it * 3 + 1], iz = pos[it * 3 + 2];
  float dx = tx - sx, dy = ty - sy, dz = tz - sz;
  float dist1 = sqrtf(dx * dx + dy * dy + dz * dz);
  float ax = tx - ix, ay = ty - iy, az = tz - iz;
  float dist2 = sqrtf(ax * ax + ay * ay + az * az);
  float bx = sx - ix, by = sy - iy, bz = sz - iz;
  float dist_ = sqrtf(bx * bx + by * by + bz * bz);
  int idx1 = bsearch31(bnd, dist1);
  int idx2 = bsearch31(bnd, dist2);
  int idx_ = bsearch31(bnd, dist_);
  const float4 A = *((const float4*)(q1 + (s * H + h) * 64) + c);
  const float4 B = *((const float4*)(q2 + (it * H + h) * 64) + c);
  const float4 C = *((const float4*)(q3 + (t * H + h) * 64) + c);
  const float4 X = *((const float4*)(U + (h * 32 + idx1) * 64) + c);
  const float4 Y = *((const float4*)(U + 8192 + (h * 32 + idx2) * 64) + c);
  const float4 Z = *((const float4*)(U + 16384 + (h * 32 + idx_) * 64) + c);
  const float4 a4 = *((const float4*)(aout + h * 64) + c);
  float t0 = fast_tanh(A.x + B.x + C.x + X.x + Y.x + Z.x);
  float t1 = fast_tanh(A.y + B.y + C.y + X.y + Y.y + Z.y);
  float t2 = fast_tanh(A.z + B.z + C.z + X.z + Y.z + Z.z);
  float t3 = fast_tanh(A.w + B.w + C.w + X.w + Y.w + Z.w);
  float v = t0 * a4.x + t1 * a4.y + t2 * a4.z + t3 * a4.w;
  #pragma unroll
  for (int off = 8; off > 0; off >>= 1) v += __shfl_xor(v, off);
  if (c == 0) escore[e * H + h] = v;
}

// ---------------------------------------------------------------------------
// K4: per-node softmax + weighted aggregation + head mean.
// One block per node; wave = head; lane = d. 4-way unrolled degree loop.
// ---------------------------------------------------------------------------
__global__ __launch_bounds__(256) void agg_kernel(
    const int* __restrict__ starts, const int* __restrict__ elist,
    const int* __restrict__ src, const float* __restrict__ escore,
    const float* __restrict__ hbuf, float* __restrict__ out) {
  __shared__ float red[H][64];
  int n = blockIdx.x;
  int h = threadIdx.x >> 6;
  int lane = threadIdx.x & 63;
  int b = starts[n], eend = starts[n + 1];
  float m = -INFINITY;
  for (int i = b + lane; i < eend; i += 64)
    m = fmaxf(m, escore[elist[i] * H + h]);
  #pragma unroll
  for (int off = 32; off > 0; off >>= 1) m = fmaxf(m, __shfl_xor(m, off));
  float den = 0.f, num = 0.f;
  int i = b;
  for (; i + 4 <= eend; i += 4) {
    int e0 = elist[i], e1 = elist[i + 1], e2 = elist[i + 2], e3 = elist[i + 3];
    float s0 = escore[e0 * H + h], s1 = escore[e1 * H + h];
    float s2 = escore[e2 * H + h], s3 = escore[e3 * H + h];
    int n0 = src[e0], n1 = src[e1], n2 = src[e2], n3 = src[e3];
    float g0 = hbuf[n0 * 256 + h * 64 + lane];
    float g1 = hbuf[n1 * 256 + h * 64 + lane];
    float g2 = hbuf[n2 * 256 + h * 64 + lane];
    float g3 = hbuf[n3 * 256 + h * 64 + lane];
    float x0 = __expf(s0 - m), x1 = __expf(s1 - m);
    float x2 = __expf(s2 - m), x3 = __expf(s3 - m);
    den += (x0 + x1) + (x2 + x3);
    num += x0 * g0;
    num += x1 * g1;
    num += x2 * g2;
    num += x3 * g3;
  }
  for (; i < eend; ++i) {
    int e = elist[i];
    float ex = __expf(escore[e * H + h] - m);
    den += ex;
    num += ex * hbuf[src[e] * 256 + h * 64 + lane];
  }
  red[h][lane] = (eend > b) ? (num / den) : 0.f;
  __syncthreads();
  if (threadIdx.x < 64) {
    out[n * 64 + lane] =
        0.25f * (red[0][lane] + red[1][lane] + red[2][lane] + red[3][lane]);
  }
}

// ---------------------------------------------------------------------------
extern "C" void kernel_launch(void* const* d_in, const int* in_sizes, int n_in,
                              void* d_out, int out_size, void* d_ws,
                              size_t ws_size, hipStream_t stream) {
  const float* feat = (const float*)d_in[0];
  const float* loc = (const float*)d_in[1];
  const int* src = (const int*)d_in[2];
  const int* dst = (const int*)d_in[3];
  const int* inter = (const int*)d_in[4];
  const float* Wfc = (const float*)d_in[5];
  const float* emb = (const float*)d_in[6];
  const float* G = (const float*)d_in[7];
  const float* fc1 = (const float*)d_in[8];
  const float* fc2 = (const float*)d_in[9];
  const float* fc3 = (const float*)d_in[10];
  const float* fcc = (const float*)d_in[11];
  const float* aout = (const float*)d_in[12];
  const float* bnd = (const float*)d_in[13];
  float* out = (float*)d_out;

  // workspace carve (floats)
  float* ws = (float*)d_ws;
  float* hbuf = ws;                       // N*256
  float* q1 = hbuf + N_NODES * HD;
  float* q2 = q1 + N_NODES * HD;
  float* q3 = q2 + N_NODES * HD;
  float* Cbuf = q3 + N_NODES * HD;        // 3*4*4096
  float* Ubuf = Cbuf + 3 * H * 4096;      // 3*4*2048
  float* escore = Ubuf + 3 * H * 2048;    // E*H
  int* counts = (int*)(escore + E_EDGES * H);  // N
  int* starts = counts + N_NODES;              // N+1
  int* cursor = starts + N_NODES + 1;          // N
  int* elist = cursor + N_NODES;               // E

  hipMemsetAsync(counts, 0, N_NODES * sizeof(int), stream);
  precompute_kernel<<<12, 256, 0, stream>>>(fc1, fc2, fc3, fcc, G, emb, Cbuf,
                                            Ubuf);
  node_kernel<<<N_NODES / 8, 256, 0, stream>>>(feat, Wfc, Cbuf, hbuf, q1, q2,
                                               q3);
  count_kernel<<<(E_EDGES + 255) / 256, 256, 0, stream>>>(dst, counts);
  scan_kernel<<<1, 1024, 0, stream>>>(counts, starts, cursor);
  fill_kernel<<<(E_EDGES + 255) / 256, 256, 0, stream>>>(dst, cursor, elist);
  edge_kernel<<<E_EDGES / 4, 256, 0, stream>>>(src, dst, inter, loc, bnd, q1,
                                               q2, q3, Ubuf, aout, escore);
  agg_kernel<<<N_NODES, 256, 0, stream>>>(starts, elist, src, escore, hbuf,
                                          out);
}

// Round 3
// 321.363 us; speedup vs baseline: 1.4282x; 1.0227x over previous
//
#include <hip/hip_runtime.h>
#include <math.h>

#define N_NODES 10000
#define E_EDGES 160000
#define IN_FEATS 128
#define DMODEL 64
#define H 4
#define NBOUND 31

// qall record per node: [0:256)=h, [256:512)=q1, [512:768)=q2, [768:1024)=q3
#define QREC 1024

// ---------------------------------------------------------------------------
// K0: precompute. Per (k,h) block:
//   F = attn_fc[h][k*64:(k+1)*64, :]          (64x64)
//   B = attn_fc{k}[h] (128x64) @ F            (128x64)
//   U_k[h] = embed @ (G[h] @ B[64:128])       (32x64)
//   WC_k[h] = Wfc[:, h*64:(h+1)*64] @ B[0:64] (128x64)  -> bigW block k+1
//   k==0 also copies Wfc slice into bigW block 0.
// ---------------------------------------------------------------------------
__global__ __launch_bounds__(256) void precompute_kernel(
    const float* __restrict__ fc1, const float* __restrict__ fc2,
    const float* __restrict__ fc3, const float* __restrict__ fcc,
    const float* __restrict__ G, const float* __restrict__ emb,
    const float* __restrict__ Wfc, float* __restrict__ bigW,
    float* __restrict__ Ubuf) {
  __shared__ float Flds[64 * 64];
  __shared__ float Blds[128 * 64];
  __shared__ float GBlds[32 * 64];
  int k = blockIdx.x >> 2;
  int h = blockIdx.x & 3;
  const float* fck = (k == 0) ? fc1 : (k == 1) ? fc2 : fc3;
  fck += h * 128 * 64;
  const float* F = fcc + h * 192 * 64 + k * 64 * 64;
  int tid = threadIdx.x;
  for (int x = tid; x < 64 * 64; x += 256) Flds[x] = F[x];
  __syncthreads();
  int j = tid & 63;
  int wv = tid >> 6;
  // B = fck @ F
  for (int ii = 0; ii < 32; ++ii) {
    int i = wv * 32 + ii;
    float acc = 0.f;
    #pragma unroll 8
    for (int t = 0; t < 64; ++t) acc += fck[i * 64 + t] * Flds[t * 64 + j];
    Blds[i * 64 + j] = acc;
  }
  __syncthreads();
  // U path
  for (int id = tid; id < 32 * 64; id += 256) {
    int g = id >> 6, jj = id & 63;
    float acc = 0.f;
    #pragma unroll 8
    for (int dd = 0; dd < 64; ++dd)
      acc += G[h * 2048 + g * 64 + dd] * Blds[(64 + dd) * 64 + jj];
    GBlds[id] = acc;
  }
  __syncthreads();
  for (int id = tid; id < 32 * 64; id += 256) {
    int ie = id >> 6, jj = id & 63;
    float acc = 0.f;
    #pragma unroll 8
    for (int g = 0; g < 32; ++g)
      acc += emb[ie * 32 + g] * GBlds[g * 64 + jj];
    Ubuf[k * 8192 + h * 2048 + id] = acc;
  }
  // WC = Wfc_h @ B[0:64]; thread owns col j, rows i = wv*32 .. +31
  float acc[32];
  #pragma unroll
  for (int ii = 0; ii < 32; ++ii) acc[ii] = 0.f;
  for (int tc = 0; tc < 64; tc += 16) {
    float Bcol[16];
    #pragma unroll
    for (int tt = 0; tt < 16; ++tt) Bcol[tt] = Blds[(tc + tt) * 64 + j];
    #pragma unroll
    for (int ii = 0; ii < 32; ++ii) {
      int i = wv * 32 + ii;
      #pragma unroll
      for (int tt = 0; tt < 16; ++tt)
        acc[ii] += Wfc[i * 256 + h * 64 + tc + tt] * Bcol[tt];
    }
  }
  #pragma unroll
  for (int ii = 0; ii < 32; ++ii) {
    int i = wv * 32 + ii;
    bigW[i * QREC + (k + 1) * 256 + h * 64 + j] = acc[ii];
    if (k == 0) bigW[i * QREC + h * 64 + j] = Wfc[i * 256 + h * 64 + j];
  }
}

// ---------------------------------------------------------------------------
// K1: qall = feat (10000x128) @ bigW (128x1024).
// Block: 64 rows x 64 cols tile; thread = 4x4 microtile; B staged in LDS,
// A read from global (16-lane broadcast, L1-hot).
// ---------------------------------------------------------------------------
__device__ __forceinline__ void fma4(float4& a, float s, const float4& b) {
  a.x += s * b.x; a.y += s * b.y; a.z += s * b.z; a.w += s * b.w;
}

__global__ __launch_bounds__(256) void gemm_kernel(
    const float* __restrict__ feat, const float* __restrict__ bigW,
    float* __restrict__ qall) {
  __shared__ float Bs[128 * 64];
  int tid = threadIdx.x;
  int m0 = blockIdx.x * 64;
  int n0 = blockIdx.y * 64;
  #pragma unroll
  for (int u = 0; u < 32; ++u) {
    int idx = u * 256 + tid;
    int kk = idx >> 6, nn = idx & 63;
    Bs[idx] = bigW[kk * QREC + n0 + nn];
  }
  __syncthreads();
  int tx = tid & 15, ty = tid >> 4;
  int mrow[4];
  #pragma unroll
  for (int im = 0; im < 4; ++im) {
    int m = m0 + ty * 4 + im;
    mrow[im] = (m < N_NODES) ? m : (N_NODES - 1);
  }
  float4 acc[4];
  #pragma unroll
  for (int im = 0; im < 4; ++im) acc[im] = make_float4(0.f, 0.f, 0.f, 0.f);
  for (int k4 = 0; k4 < 32; ++k4) {
    float4 a[4];
    #pragma unroll
    for (int im = 0; im < 4; ++im)
      a[im] = *(const float4*)&feat[mrow[im] * 128 + k4 * 4];
    float4 b[4];
    #pragma unroll
    for (int ik = 0; ik < 4; ++ik)
      b[ik] = *(const float4*)&Bs[(k4 * 4 + ik) * 64 + tx * 4];
    #pragma unroll
    for (int im = 0; im < 4; ++im) {
      fma4(acc[im], a[im].x, b[0]);
      fma4(acc[im], a[im].y, b[1]);
      fma4(acc[im], a[im].z, b[2]);
      fma4(acc[im], a[im].w, b[3]);
    }
  }
  #pragma unroll
  for (int im = 0; im < 4; ++im) {
    int m = m0 + ty * 4 + im;
    if (m < N_NODES) *(float4*)&qall[m * QREC + n0 + tx * 4] = acc[im];
  }
}

// ---------------------------------------------------------------------------
// CSR build
// ---------------------------------------------------------------------------
__global__ __launch_bounds__(256) void count_kernel(const int* __restrict__ dst,
                                                    int* __restrict__ counts) {
  int e = blockIdx.x * 256 + threadIdx.x;
  if (e < E_EDGES) atomicAdd(&counts[dst[e]], 1);
}

__global__ __launch_bounds__(1024) void scan_kernel(const int* __restrict__ counts,
                                                    int* __restrict__ starts,
                                                    int* __restrict__ cursor) {
  __shared__ int lds[1024];
  int tid = threadIdx.x;
  int base = tid * 10;
  int loc[10];
  int s = 0;
  #pragma unroll
  for (int u = 0; u < 10; ++u) {
    int i = base + u;
    int v = (i < N_NODES) ? counts[i] : 0;
    loc[u] = s;
    s += v;
  }
  lds[tid] = s;
  __syncthreads();
  int inc = s;
  for (int off = 1; off < 1024; off <<= 1) {
    int y = (tid >= off) ? lds[tid - off] : 0;
    __syncthreads();
    inc += y;
    lds[tid] = inc;
    __syncthreads();
  }
  int excl = inc - s;
  #pragma unroll
  for (int u = 0; u < 10; ++u) {
    int i = base + u;
    if (i < N_NODES) {
      int v = excl + loc[u];
      starts[i] = v;
      cursor[i] = v;
    }
  }
  if (tid == 1023) starts[N_NODES] = inc;
}

__global__ __launch_bounds__(256) void fill_kernel(const int* __restrict__ dst,
                                                   int* __restrict__ cursor,
                                                   int* __restrict__ elist) {
  int e = blockIdx.x * 256 + threadIdx.x;
  if (e < E_EDGES) {
    int p = atomicAdd(&cursor[dst[e]], 1);
    elist[p] = e;
  }
}

// ---------------------------------------------------------------------------
// K3: FUSED score + softmax + aggregate. Block = dst node. 4 waves, each
// wave handles edges i = b+w, b+w+4, ... covering all 4 heads via lane
// layout (h = lane>>4, c = lane&15, float4 over d).
// Max-free softmax: |score| <= sum|aout| ~ 15 -> exp cannot overflow fp32.
// ---------------------------------------------------------------------------

// searchsorted-left over uniform linspace(0.1,3.1,31): estimate + exact fix.
// bnd2[0] = -inf, bnd2[1..31] = boundaries, bnd2[32] = +inf.
__device__ __forceinline__ int didx(const float* __restrict__ bnd2, float d) {
  int g = (int)(d * 10.0f);
  g = (g < 0) ? 0 : ((g > 31) ? 31 : g);
  g += (bnd2[g + 1] < d) ? 1 : 0;   // estimate one too low
  g -= (bnd2[g] >= d) ? 1 : 0;      // estimate one too high
  return g;
}

// branchless tanh: copysign(1 - 2/(e^{2|z|}+1), z)
__device__ __forceinline__ float fast_tanh(float z) {
  float a = fabsf(z);
  float p = __expf(2.0f * a);
  float r = 1.0f - 2.0f / (p + 1.0f);
  return copysignf(r, z);
}

__global__ __launch_bounds__(256) void fused_kernel(
    const int* __restrict__ starts, const int* __restrict__ elist,
    const int* __restrict__ src, const int* __restrict__ inter,
    const float* __restrict__ pos, const float* __restrict__ boundaries,
    const float* __restrict__ qall, const float* __restrict__ U,
    const float* __restrict__ aout, float* __restrict__ out) {
  __shared__ float bnd2[33];
  __shared__ float4 sm_num[4][64];
  __shared__ float sm_den[4][4];
  __shared__ float sm_red[4][64];
  int tid = threadIdx.x;
  if (tid < NBOUND) bnd2[tid + 1] = boundaries[tid];
  if (tid == NBOUND) { bnd2[0] = -INFINITY; bnd2[32] = INFINITY; }
  __syncthreads();
  int w = tid >> 6;
  int lane = tid & 63;
  int h = lane >> 4;
  int c = lane & 15;
  int n = blockIdx.x;
  int b = starts[n], e_end = starts[n + 1];
  float tx = pos[n * 3], ty = pos[n * 3 + 1], tz = pos[n * 3 + 2];
  const float4 q3f = *((const float4*)(qall + n * QREC + 768 + h * 64) + c);
  const float4 a4 = *((const float4*)(aout + h * 64) + c);
  float4 acc = make_float4(0.f, 0.f, 0.f, 0.f);
  float den = 0.f;
  for (int i = b + w; i < e_end; i += 4) {
    int e = elist[i];
    int s = src[e];
    int it = inter[e * H + h];
    float sx = pos[s * 3], sy = pos[s * 3 + 1], sz = pos[s * 3 + 2];
    float ix = pos[it * 3], iy = pos[it * 3 + 1], iz = pos[it * 3 + 2];
    float dx = tx - sx, dy = ty - sy, dz = tz - sz;
    float dist1 = sqrtf(dx * dx + dy * dy + dz * dz);
    float ax = tx - ix, ay = ty - iy, az = tz - iz;
    float dist2 = sqrtf(ax * ax + ay * ay + az * az);
    float bx = sx - ix, by = sy - iy, bz = sz - iz;
    float dist_ = sqrtf(bx * bx + by * by + bz * bz);
    int idx1 = didx(bnd2, dist1);
    int idx2 = didx(bnd2, dist2);
    int idx_ = didx(bnd2, dist_);
    const float4 A = *((const float4*)(qall + s * QREC + 256 + h * 64) + c);
    const float4 B = *((const float4*)(qall + it * QREC + 512 + h * 64) + c);
    const float4 X = *((const float4*)(U + (h * 32 + idx1) * 64) + c);
    const float4 Y = *((const float4*)(U + 8192 + (h * 32 + idx2) * 64) + c);
    const float4 Z = *((const float4*)(U + 16384 + (h * 32 + idx_) * 64) + c);
    float t0 = fast_tanh(A.x + B.x + q3f.x + X.x + Y.x + Z.x);
    float t1 = fast_tanh(A.y + B.y + q3f.y + X.y + Y.y + Z.y);
    float t2 = fast_tanh(A.z + B.z + q3f.z + X.z + Y.z + Z.z);
    float t3 = fast_tanh(A.w + B.w + q3f.w + X.w + Y.w + Z.w);
    float v = t0 * a4.x + t1 * a4.y + t2 * a4.z + t3 * a4.w;
    #pragma unroll
    for (int off = 8; off > 0; off >>= 1) v += __shfl_xor(v, off);
    float ex = __expf(v);
    den += ex;
    const float4 hb = *((const float4*)(qall + s * QREC + h * 64) + c);
    fma4(acc, ex, hb);
  }
  sm_num[w][lane] = acc;
  if (c == 0) sm_den[w][h] = den;
  __syncthreads();
  // combine partials: thread -> (head hh, element d)
  int hh = tid >> 6, d = tid & 63;
  float dsum = sm_den[0][hh] + sm_den[1][hh] + sm_den[2][hh] + sm_den[3][hh];
  float v = 0.f;
  #pragma unroll
  for (int wv = 0; wv < 4; ++wv)
    v += ((const float*)&sm_num[wv][hh * 16 + (d >> 2)])[d & 3];
  sm_red[hh][d] = (e_end > b) ? (v / dsum) : 0.f;
  __syncthreads();
  if (tid < 64) {
    out[n * 64 + tid] = 0.25f * (sm_red[0][tid] + sm_red[1][tid] +
                                 sm_red[2][tid] + sm_red[3][tid]);
  }
}

// ---------------------------------------------------------------------------
extern "C" void kernel_launch(void* const* d_in, const int* in_sizes, int n_in,
                              void* d_out, int out_size, void* d_ws,
                              size_t ws_size, hipStream_t stream) {
  const float* feat = (const float*)d_in[0];
  const float* loc = (const float*)d_in[1];
  const int* src = (const int*)d_in[2];
  const int* dst = (const int*)d_in[3];
  const int* inter = (const int*)d_in[4];
  const float* Wfc = (const float*)d_in[5];
  const float* emb = (const float*)d_in[6];
  const float* G = (const float*)d_in[7];
  const float* fc1 = (const float*)d_in[8];
  const float* fc2 = (const float*)d_in[9];
  const float* fc3 = (const float*)d_in[10];
  const float* fcc = (const float*)d_in[11];
  const float* aout = (const float*)d_in[12];
  const float* bnd = (const float*)d_in[13];
  float* out = (float*)d_out;

  float* ws = (float*)d_ws;
  float* qall = ws;                          // N*1024 floats
  float* bigW = qall + N_NODES * QREC;       // 128*1024
  float* Ubuf = bigW + 128 * QREC;           // 3*4*2048
  int* counts = (int*)(Ubuf + 3 * H * 2048); // N
  int* starts = counts + N_NODES;            // N+1
  int* cursor = starts + N_NODES + 1;        // N
  int* elist = cursor + N_NODES;             // E

  hipMemsetAsync(counts, 0, N_NODES * sizeof(int), stream);
  precompute_kernel<<<12, 256, 0, stream>>>(fc1, fc2, fc3, fcc, G, emb, Wfc,
                                            bigW, Ubuf);
  count_kernel<<<(E_EDGES + 255) / 256, 256, 0, stream>>>(dst, counts);
  dim3 ggrid((N_NODES + 63) / 64, 16);
  gemm_kernel<<<ggrid, 256, 0, stream>>>(feat, bigW, qall);
  scan_kernel<<<1, 1024, 0, stream>>>(counts, starts, cursor);
  fill_kernel<<<(E_EDGES + 255) / 256, 256, 0, stream>>>(dst, cursor, elist);
  fused_kernel<<<N_NODES, 256, 0, stream>>>(starts, elist, src, inter, loc,
                                            bnd, qall, Ubuf, aout, out);
}

// Round 4
// 254.946 us; speedup vs baseline: 1.8002x; 1.2605x over previous
//
#include <hip/hip_runtime.h>
#include <hip/hip_fp16.h>
#include <math.h>

#define N_NODES 10000
#define E_EDGES 160000
#define IN_FEATS 128
#define DMODEL 64
#define H 4
#define NBOUND 31

// qall record per node (fp16): [0:256)=h, [256:512)=q1, [512:768)=q2, [768:1024)=q3
#define QREC 1024

// ---------------------------------------------------------------------------
// K0: precompute, 36 blocks = 12 (k,h) x 3 roles.
//  role 0: B1 = fck[0:64] @ F;  WC rows 0-63  = Wfc_h[0:64]  @ B1 -> bigW
//  role 1: B1 = fck[0:64] @ F;  WC rows 64-127= Wfc_h[64:128]@ B1 -> bigW
//  role 2: B2 = fck[64:128]@ F; GB = G_h @ B2; U = emb @ GB       -> Ubuf
//  k==0 roles 0/1 also copy Wfc slice into bigW block 0.
// All operands LDS-staged; B computed in place (wave-row partition).
// ---------------------------------------------------------------------------
__global__ __launch_bounds__(256) void precompute_kernel(
    const float* __restrict__ fc1, const float* __restrict__ fc2,
    const float* __restrict__ fc3, const float* __restrict__ fcc,
    const float* __restrict__ G, const float* __restrict__ emb,
    const float* __restrict__ Wfc, float* __restrict__ bigW,
    float* __restrict__ Ubuf) {
  __shared__ float S[13312];  // [0:4096) B, [4096:8192) F/GB, [8192:12288) op, [10240:11264) emb region for role2
  int bi = blockIdx.x;
  int role = bi % 3;
  int kh = bi / 3;
  int k = kh >> 2;
  int h = kh & 3;
  const float* fck = (k == 0) ? fc1 : (k == 1) ? fc2 : fc3;
  fck += h * 128 * 64;
  const float* F = fcc + h * 192 * 64 + k * 64 * 64;
  int tid = threadIdx.x;
  int wv = tid >> 6;
  int j = tid & 63;

  // stage F -> S[4096:8192), fck half -> S[0:4096)
  int fckoff = (role == 2) ? 64 * 64 : 0;
  #pragma unroll
  for (int u = 0; u < 16; ++u) {
    int idx = u * 256 + tid;
    S[4096 + idx] = F[idx];
    S[idx] = fck[fckoff + idx];
  }
  __syncthreads();

  // B half in place: rows wv*16..+15, 4-row groups, b128 broadcasts of fck.
  #pragma unroll
  for (int rg = 0; rg < 4; ++rg) {
    int i0 = wv * 16 + rg * 4;
    float a0 = 0.f, a1 = 0.f, a2 = 0.f, a3 = 0.f;
    #pragma unroll
    for (int t4 = 0; t4 < 16; ++t4) {
      float4 f0 = *(const float4*)&S[(i0 + 0) * 64 + t4 * 4];
      float4 f1 = *(const float4*)&S[(i0 + 1) * 64 + t4 * 4];
      float4 f2 = *(const float4*)&S[(i0 + 2) * 64 + t4 * 4];
      float4 f3 = *(const float4*)&S[(i0 + 3) * 64 + t4 * 4];
      float b0 = S[4096 + (t4 * 4 + 0) * 64 + j];
      float b1 = S[4096 + (t4 * 4 + 1) * 64 + j];
      float b2 = S[4096 + (t4 * 4 + 2) * 64 + j];
      float b3 = S[4096 + (t4 * 4 + 3) * 64 + j];
      a0 += f0.x * b0 + f0.y * b1 + f0.z * b2 + f0.w * b3;
      a1 += f1.x * b0 + f1.y * b1 + f1.z * b2 + f1.w * b3;
      a2 += f2.x * b0 + f2.y * b1 + f2.z * b2 + f2.w * b3;
      a3 += f3.x * b0 + f3.y * b1 + f3.z * b2 + f3.w * b3;
    }
    S[(i0 + 0) * 64 + j] = a0;
    S[(i0 + 1) * 64 + j] = a1;
    S[(i0 + 2) * 64 + j] = a2;
    S[(i0 + 3) * 64 + j] = a3;
  }
  __syncthreads();

  if (role < 2) {
    // stage Wfc half rows (role*64 .. +63), col slice h -> S[8192:12288)
    int r0 = role * 64;
    #pragma unroll
    for (int u = 0; u < 16; ++u) {
      int idx = u * 256 + tid;
      int i = idx >> 6, jj = idx & 63;
      float v = Wfc[(r0 + i) * 256 + h * 64 + jj];
      S[8192 + idx] = v;
      if (k == 0) bigW[(r0 + i) * QREC + h * 64 + jj] = v;
    }
    __syncthreads();
    // WC[i][j] = sum_t WfcS[i][t] * B[t][j]
    #pragma unroll
    for (int rg = 0; rg < 4; ++rg) {
      int i0 = wv * 16 + rg * 4;
      float a0 = 0.f, a1 = 0.f, a2 = 0.f, a3 = 0.f;
      #pragma unroll
      for (int t4 = 0; t4 < 16; ++t4) {
        float4 f0 = *(const float4*)&S[8192 + (i0 + 0) * 64 + t4 * 4];
        float4 f1 = *(const float4*)&S[8192 + (i0 + 1) * 64 + t4 * 4];
        float4 f2 = *(const float4*)&S[8192 + (i0 + 2) * 64 + t4 * 4];
        float4 f3 = *(const float4*)&S[8192 + (i0 + 3) * 64 + t4 * 4];
        float b0 = S[(t4 * 4 + 0) * 64 + j];
        float b1 = S[(t4 * 4 + 1) * 64 + j];
        float b2 = S[(t4 * 4 + 2) * 64 + j];
        float b3 = S[(t4 * 4 + 3) * 64 + j];
        a0 += f0.x * b0 + f0.y * b1 + f0.z * b2 + f0.w * b3;
        a1 += f1.x * b0 + f1.y * b1 + f1.z * b2 + f1.w * b3;
        a2 += f2.x * b0 + f2.y * b1 + f2.z * b2 + f2.w * b3;
        a3 += f3.x * b0 + f3.y * b1 + f3.z * b2 + f3.w * b3;
      }
      bigW[(r0 + i0 + 0) * QREC + (k + 1) * 256 + h * 64 + j] = a0;
      bigW[(r0 + i0 + 1) * QREC + (k + 1) * 256 + h * 64 + j] = a1;
      bigW[(r0 + i0 + 2) * QREC + (k + 1) * 256 + h * 64 + j] = a2;
      bigW[(r0 + i0 + 3) * QREC + (k + 1) * 256 + h * 64 + j] = a3;
    }
  } else {
    // stage G_h (2048) -> S[8192:10240), emb (1024) -> S[10240:11264)
    #pragma unroll
    for (int u = 0; u < 8; ++u) S[8192 + u * 256 + tid] = G[h * 2048 + u * 256 + tid];
    #pragma unroll
    for (int u = 0; u < 4; ++u) S[10240 + u * 256 + tid] = emb[u * 256 + tid];
    __syncthreads();
    // GB[g][j] = sum_dd G[g][dd] * B2[dd][j]  (32x64) -> S[4096:6144)
    #pragma unroll
    for (int rg = 0; rg < 2; ++rg) {
      int g0 = wv * 8 + rg * 4;
      float a0 = 0.f, a1 = 0.f, a2 = 0.f, a3 = 0.f;
      #pragma unroll
      for (int t4 = 0; t4 < 16; ++t4) {
        float4 f0 = *(const float4*)&S[8192 + (g0 + 0) * 64 + t4 * 4];
        float4 f1 = *(const float4*)&S[8192 + (g0 + 1) * 64 + t4 * 4];
        float4 f2 = *(const float4*)&S[8192 + (g0 + 2) * 64 + t4 * 4];
        float4 f3 = *(const float4*)&S[8192 + (g0 + 3) * 64 + t4 * 4];
        float b0 = S[(t4 * 4 + 0) * 64 + j];
        float b1 = S[(t4 * 4 + 1) * 64 + j];
        float b2 = S[(t4 * 4 + 2) * 64 + j];
        float b3 = S[(t4 * 4 + 3) * 64 + j];
        a0 += f0.x * b0 + f0.y * b1 + f0.z * b2 + f0.w * b3;
        a1 += f1.x * b0 + f1.y * b1 + f1.z * b2 + f1.w * b3;
        a2 += f2.x * b0 + f2.y * b1 + f2.z * b2 + f2.w * b3;
        a3 += f3.x * b0 + f3.y * b1 + f3.z * b2 + f3.w * b3;
      }
      S[4096 + (g0 + 0) * 64 + j] = a0;
      S[4096 + (g0 + 1) * 64 + j] = a1;
      S[4096 + (g0 + 2) * 64 + j] = a2;
      S[4096 + (g0 + 3) * 64 + j] = a3;
    }
    __syncthreads();
    // U[ie][j] = sum_g emb[ie*32+g] * GB[g][j] -> Ubuf
    #pragma unroll
    for (int rg = 0; rg < 2; ++rg) {
      int e0 = wv * 8 + rg * 4;
      float a0 = 0.f, a1 = 0.f, a2 = 0.f, a3 = 0.f;
      #pragma unroll
      for (int t4 = 0; t4 < 8; ++t4) {
        float4 f0 = *(const float4*)&S[10240 + (e0 + 0) * 32 + t4 * 4];
        float4 f1 = *(const float4*)&S[10240 + (e0 + 1) * 32 + t4 * 4];
        float4 f2 = *(const float4*)&S[10240 + (e0 + 2) * 32 + t4 * 4];
        float4 f3 = *(const float4*)&S[10240 + (e0 + 3) * 32 + t4 * 4];
        float b0 = S[4096 + (t4 * 4 + 0) * 64 + j];
        float b1 = S[4096 + (t4 * 4 + 1) * 64 + j];
        float b2 = S[4096 + (t4 * 4 + 2) * 64 + j];
        float b3 = S[4096 + (t4 * 4 + 3) * 64 + j];
        a0 += f0.x * b0 + f0.y * b1 + f0.z * b2 + f0.w * b3;
        a1 += f1.x * b0 + f1.y * b1 + f1.z * b2 + f1.w * b3;
        a2 += f2.x * b0 + f2.y * b1 + f2.z * b2 + f2.w * b3;
        a3 += f3.x * b0 + f3.y * b1 + f3.z * b2 + f3.w * b3;
      }
      Ubuf[k * 8192 + h * 2048 + (e0 + 0) * 64 + j] = a0;
      Ubuf[k * 8192 + h * 2048 + (e0 + 1) * 64 + j] = a1;
      Ubuf[k * 8192 + h * 2048 + (e0 + 2) * 64 + j] = a2;
      Ubuf[k * 8192 + h * 2048 + (e0 + 3) * 64 + j] = a3;
    }
  }
}

// ---------------------------------------------------------------------------
// K1: qall(fp16) = feat (10000x128) @ bigW (128x1024).
// ---------------------------------------------------------------------------
__device__ __forceinline__ void fma4(float4& a, float s, const float4& b) {
  a.x += s * b.x; a.y += s * b.y; a.z += s * b.z; a.w += s * b.w;
}

__global__ __launch_bounds__(256) void gemm_kernel(
    const float* __restrict__ feat, const float* __restrict__ bigW,
    __half* __restrict__ qall) {
  __shared__ float Bs[128 * 64];
  int tid = threadIdx.x;
  int m0 = blockIdx.x * 64;
  int n0 = blockIdx.y * 64;
  #pragma unroll
  for (int u = 0; u < 32; ++u) {
    int idx = u * 256 + tid;
    int kk = idx >> 6, nn = idx & 63;
    Bs[idx] = bigW[kk * QREC + n0 + nn];
  }
  __syncthreads();
  int tx = tid & 15, ty = tid >> 4;
  int mrow[4];
  #pragma unroll
  for (int im = 0; im < 4; ++im) {
    int m = m0 + ty * 4 + im;
    mrow[im] = (m < N_NODES) ? m : (N_NODES - 1);
  }
  float4 acc[4];
  #pragma unroll
  for (int im = 0; im < 4; ++im) acc[im] = make_float4(0.f, 0.f, 0.f, 0.f);
  for (int k4 = 0; k4 < 32; ++k4) {
    float4 a[4];
    #pragma unroll
    for (int im = 0; im < 4; ++im)
      a[im] = *(const float4*)&feat[mrow[im] * 128 + k4 * 4];
    float4 b[4];
    #pragma unroll
    for (int ik = 0; ik < 4; ++ik)
      b[ik] = *(const float4*)&Bs[(k4 * 4 + ik) * 64 + tx * 4];
    #pragma unroll
    for (int im = 0; im < 4; ++im) {
      fma4(acc[im], a[im].x, b[0]);
      fma4(acc[im], a[im].y, b[1]);
      fma4(acc[im], a[im].z, b[2]);
      fma4(acc[im], a[im].w, b[3]);
    }
  }
  #pragma unroll
  for (int im = 0; im < 4; ++im) {
    int m = m0 + ty * 4 + im;
    if (m < N_NODES) {
      union { uint2 u; __half2 h[2]; } st;
      st.h[0] = __floats2half2_rn(acc[im].x, acc[im].y);
      st.h[1] = __floats2half2_rn(acc[im].z, acc[im].w);
      *(uint2*)&qall[m * QREC + n0 + tx * 4] = st.u;
    }
  }
}

// ---------------------------------------------------------------------------
// CSR build
// ---------------------------------------------------------------------------
__global__ __launch_bounds__(256) void count_kernel(const int* __restrict__ dst,
                                                    int* __restrict__ counts) {
  int e = blockIdx.x * 256 + threadIdx.x;
  if (e < E_EDGES) atomicAdd(&counts[dst[e]], 1);
}

__global__ __launch_bounds__(1024) void scan_kernel(const int* __restrict__ counts,
                                                    int* __restrict__ starts,
                                                    int* __restrict__ cursor) {
  __shared__ int lds[1024];
  int tid = threadIdx.x;
  int base = tid * 10;
  int loc[10];
  int s = 0;
  #pragma unroll
  for (int u = 0; u < 10; ++u) {
    int i = base + u;
    int v = (i < N_NODES) ? counts[i] : 0;
    loc[u] = s;
    s += v;
  }
  lds[tid] = s;
  __syncthreads();
  int inc = s;
  for (int off = 1; off < 1024; off <<= 1) {
    int y = (tid >= off) ? lds[tid - off] : 0;
    __syncthreads();
    inc += y;
    lds[tid] = inc;
    __syncthreads();
  }
  int excl = inc - s;
  #pragma unroll
  for (int u = 0; u < 10; ++u) {
    int i = base + u;
    if (i < N_NODES) {
      int v = excl + loc[u];
      starts[i] = v;
      cursor[i] = v;
    }
  }
  if (tid == 1023) starts[N_NODES] = inc;
}

__global__ __launch_bounds__(256) void fill_kernel(const int* __restrict__ dst,
                                                   int* __restrict__ cursor,
                                                   int* __restrict__ elist) {
  int e = blockIdx.x * 256 + threadIdx.x;
  if (e < E_EDGES) {
    int p = atomicAdd(&cursor[dst[e]], 1);
    elist[p] = e;
  }
}

// ---------------------------------------------------------------------------
// K3: FUSED score + softmax + aggregate (max-free; |score| <= ~15).
// Block = dst node; 4 waves stride the edge list; lane: h=lane>>4, c=lane&15.
// qall is fp16; U/aout fp32 (tiny, cache-hot).
// ---------------------------------------------------------------------------
__device__ __forceinline__ int didx(const float* __restrict__ bnd2, float d) {
  int g = (int)(d * 10.0f);
  g = (g < 0) ? 0 : ((g > 31) ? 31 : g);
  g += (bnd2[g + 1] < d) ? 1 : 0;
  g -= (bnd2[g] >= d) ? 1 : 0;
  return g;
}

__device__ __forceinline__ float fast_tanh(float z) {
  float a = fabsf(z);
  float p = __expf(2.0f * a);
  float r = 1.0f - 2.0f / (p + 1.0f);
  return copysignf(r, z);
}

__device__ __forceinline__ float4 ldh4(const __half* p) {
  union { float2 f; __half2 h[2]; } u;
  u.f = *(const float2*)p;
  float2 a = __half22float2(u.h[0]);
  float2 b = __half22float2(u.h[1]);
  return make_float4(a.x, a.y, b.x, b.y);
}

__global__ __launch_bounds__(256) void fused_kernel(
    const int* __restrict__ starts, const int* __restrict__ elist,
    const int* __restrict__ src, const int* __restrict__ inter,
    const float* __restrict__ pos, const float* __restrict__ boundaries,
    const __half* __restrict__ qall, const float* __restrict__ U,
    const float* __restrict__ aout, float* __restrict__ out) {
  __shared__ float bnd2[33];
  __shared__ float4 sm_num[4][64];
  __shared__ float sm_den[4][4];
  __shared__ float sm_red[4][64];
  int tid = threadIdx.x;
  if (tid < NBOUND) bnd2[tid + 1] = boundaries[tid];
  if (tid == NBOUND) { bnd2[0] = -INFINITY; bnd2[32] = INFINITY; }
  __syncthreads();
  int w = tid >> 6;
  int lane = tid & 63;
  int h = lane >> 4;
  int c = lane & 15;
  int n = blockIdx.x;
  int b = starts[n], e_end = starts[n + 1];
  float tx = pos[n * 3], ty = pos[n * 3 + 1], tz = pos[n * 3 + 2];
  const float4 q3f = ldh4(qall + n * QREC + 768 + h * 64 + c * 4);
  const float4 a4 = *((const float4*)(aout + h * 64) + c);
  float4 acc = make_float4(0.f, 0.f, 0.f, 0.f);
  float den = 0.f;
  int i = b + w;
  int e = 0, s = 0, it = 0;
  if (i < e_end) {
    e = elist[i];
    s = src[e];
    it = inter[e * H + h];
  }
  while (i < e_end) {
    int inext = i + 4;
    int en = 0, sn = 0, itn = 0;
    if (inext < e_end) {
      en = elist[inext];
      sn = src[en];
      itn = inter[en * H + h];
    }
    float sx = pos[s * 3], sy = pos[s * 3 + 1], sz = pos[s * 3 + 2];
    float ix = pos[it * 3], iy = pos[it * 3 + 1], iz = pos[it * 3 + 2];
    float dx = tx - sx, dy = ty - sy, dz = tz - sz;
    float dist1 = sqrtf(dx * dx + dy * dy + dz * dz);
    float ax = tx - ix, ay = ty - iy, az = tz - iz;
    float dist2 = sqrtf(ax * ax + ay * ay + az * az);
    float bx = sx - ix, by = sy - iy, bz = sz - iz;
    float dist_ = sqrtf(bx * bx + by * by + bz * bz);
    int idx1 = didx(bnd2, dist1);
    int idx2 = didx(bnd2, dist2);
    int idx_ = didx(bnd2, dist_);
    const float4 A = ldh4(qall + s * QREC + 256 + h * 64 + c * 4);
    const float4 B = ldh4(qall + it * QREC + 512 + h * 64 + c * 4);
    const float4 X = *((const float4*)(U + (h * 32 + idx1) * 64) + c);
    const float4 Y = *((const float4*)(U + 8192 + (h * 32 + idx2) * 64) + c);
    const float4 Z = *((const float4*)(U + 16384 + (h * 32 + idx_) * 64) + c);
    const float4 hb = ldh4(qall + s * QREC + h * 64 + c * 4);
    float t0 = fast_tanh(A.x + B.x + q3f.x + X.x + Y.x + Z.x);
    float t1 = fast_tanh(A.y + B.y + q3f.y + X.y + Y.y + Z.y);
    float t2 = fast_tanh(A.z + B.z + q3f.z + X.z + Y.z + Z.z);
    float t3 = fast_tanh(A.w + B.w + q3f.w + X.w + Y.w + Z.w);
    float v = t0 * a4.x + t1 * a4.y + t2 * a4.z + t3 * a4.w;
    #pragma unroll
    for (int off = 8; off > 0; off >>= 1) v += __shfl_xor(v, off);
    float ex = __expf(v);
    den += ex;
    fma4(acc, ex, hb);
    i = inext;
    e = en;
    s = sn;
    it = itn;
  }
  sm_num[w][lane] = acc;
  if (c == 0) sm_den[w][h] = den;
  __syncthreads();
  int hh = tid >> 6, d = tid & 63;
  float dsum = sm_den[0][hh] + sm_den[1][hh] + sm_den[2][hh] + sm_den[3][hh];
  float v = 0.f;
  #pragma unroll
  for (int wv = 0; wv < 4; ++wv)
    v += ((const float*)&sm_num[wv][hh * 16 + (d >> 2)])[d & 3];
  sm_red[hh][d] = (e_end > b) ? (v / dsum) : 0.f;
  __syncthreads();
  if (tid < 64) {
    out[n * 64 + tid] = 0.25f * (sm_red[0][tid] + sm_red[1][tid] +
                                 sm_red[2][tid] + sm_red[3][tid]);
  }
}

// ---------------------------------------------------------------------------
extern "C" void kernel_launch(void* const* d_in, const int* in_sizes, int n_in,
                              void* d_out, int out_size, void* d_ws,
                              size_t ws_size, hipStream_t stream) {
  const float* feat = (const float*)d_in[0];
  const float* loc = (const float*)d_in[1];
  const int* src = (const int*)d_in[2];
  const int* dst = (const int*)d_in[3];
  const int* inter = (const int*)d_in[4];
  const float* Wfc = (const float*)d_in[5];
  const float* emb = (const float*)d_in[6];
  const float* G = (const float*)d_in[7];
  const float* fc1 = (const float*)d_in[8];
  const float* fc2 = (const float*)d_in[9];
  const float* fc3 = (const float*)d_in[10];
  const float* fcc = (const float*)d_in[11];
  const float* aout = (const float*)d_in[12];
  const float* bnd = (const float*)d_in[13];
  float* out = (float*)d_out;

  __half* qall = (__half*)d_ws;                         // N*1024 halves (20.48 MB)
  float* bigW = (float*)(qall + N_NODES * QREC);        // 128*1024 f32
  float* Ubuf = bigW + 128 * QREC;                      // 3*4*2048 f32
  int* counts = (int*)(Ubuf + 3 * H * 2048);            // N
  int* starts = counts + N_NODES;                       // N+1
  int* cursor = starts + N_NODES + 1;                   // N
  int* elist = cursor + N_NODES;                        // E

  hipMemsetAsync(counts, 0, N_NODES * sizeof(int), stream);
  precompute_kernel<<<36, 256, 0, stream>>>(fc1, fc2, fc3, fcc, G, emb, Wfc,
                                            bigW, Ubuf);
  count_kernel<<<(E_EDGES + 255) / 256, 256, 0, stream>>>(dst, counts);
  scan_kernel<<<1, 1024, 0, stream>>>(counts, starts, cursor);
  fill_kernel<<<(E_EDGES + 255) / 256, 256, 0, stream>>>(dst, cursor, elist);
  dim3 ggrid((N_NODES + 63) / 64, 16);
  gemm_kernel<<<ggrid, 256, 0, stream>>>(feat, bigW, qall);
  fused_kernel<<<N_NODES, 256, 0, stream>>>(starts, elist, src, inter, loc,
                                            bnd, qall, Ubuf, aout, out);
}

// Round 5
// 243.244 us; speedup vs baseline: 1.8868x; 1.0481x over previous
//
#include <hip/hip_runtime.h>
#include <hip/hip_fp16.h>
#include <math.h>

#define N_NODES 10000
#define E_EDGES 160000
#define DMODEL 64
#define H 4
#define NBOUND 31
#define QREC 1024  // per-node fp16 record: [0:256)=h,[256:512)=q1,[512:768)=q2,[768:1024)=q3

typedef _Float16 half8 __attribute__((ext_vector_type(8)));
typedef float floatx4 __attribute__((ext_vector_type(4)));

// ---------------------------------------------------------------------------
// P1: B[kh] = fck (128x64) @ F (64x64) -> Bws.  12 blocks.
// ---------------------------------------------------------------------------
__global__ __launch_bounds__(256) void pre1_kernel(
    const float* __restrict__ fc1, const float* __restrict__ fc2,
    const float* __restrict__ fc3, const float* __restrict__ fcc,
    float* __restrict__ Bws) {
  __shared__ __align__(16) float S[12288];  // [0:8192) fck, [8192:12288) F
  int kh = blockIdx.x;
  int k = kh >> 2, h = kh & 3;
  const float* fck = (k == 0) ? fc1 : (k == 1) ? fc2 : fc3;
  fck += h * 128 * 64;
  const float* F = fcc + h * 192 * 64 + k * 64 * 64;
  int tid = threadIdx.x;
  #pragma unroll
  for (int u = 0; u < 8; ++u)
    ((float4*)S)[u * 256 + tid] = ((const float4*)fck)[u * 256 + tid];
  #pragma unroll
  for (int u = 0; u < 4; ++u)
    ((float4*)(S + 8192))[u * 256 + tid] = ((const float4*)F)[u * 256 + tid];
  __syncthreads();
  int j = tid & 63, ig = tid >> 6;
  #pragma unroll
  for (int rg = 0; rg < 8; ++rg) {
    int i0 = ig * 32 + rg * 4;
    float a0 = 0.f, a1 = 0.f, a2 = 0.f, a3 = 0.f;
    #pragma unroll
    for (int t4 = 0; t4 < 16; ++t4) {
      float4 f0 = *(const float4*)&S[(i0 + 0) * 64 + t4 * 4];
      float4 f1 = *(const float4*)&S[(i0 + 1) * 64 + t4 * 4];
      float4 f2 = *(const float4*)&S[(i0 + 2) * 64 + t4 * 4];
      float4 f3 = *(const float4*)&S[(i0 + 3) * 64 + t4 * 4];
      float b0 = S[8192 + (t4 * 4 + 0) * 64 + j];
      float b1 = S[8192 + (t4 * 4 + 1) * 64 + j];
      float b2 = S[8192 + (t4 * 4 + 2) * 64 + j];
      float b3 = S[8192 + (t4 * 4 + 3) * 64 + j];
      a0 += f0.x * b0 + f0.y * b1 + f0.z * b2 + f0.w * b3;
      a1 += f1.x * b0 + f1.y * b1 + f1.z * b2 + f1.w * b3;
      a2 += f2.x * b0 + f2.y * b1 + f2.z * b2 + f2.w * b3;
      a3 += f3.x * b0 + f3.y * b1 + f3.z * b2 + f3.w * b3;
    }
    Bws[kh * 8192 + (i0 + 0) * 64 + j] = a0;
    Bws[kh * 8192 + (i0 + 1) * 64 + j] = a1;
    Bws[kh * 8192 + (i0 + 2) * 64 + j] = a2;
    Bws[kh * 8192 + (i0 + 3) * 64 + j] = a3;
  }
}

// ---------------------------------------------------------------------------
// P2: 60 blocks = 12 kh x 5 roles.
//  role 0-3: WC rows r0=role*32..+31: Wfc_h @ B1 -> bigWT (fp16, [n][k])
//            (k==0 also copies Wfc slice into bigWT block 0)
//  role 4  : GB = G_h @ B2; U = emb @ GB -> Ubuf (fp32)
// ---------------------------------------------------------------------------
__global__ __launch_bounds__(256) void pre2_kernel(
    const float* __restrict__ Wfc, const float* __restrict__ G,
    const float* __restrict__ emb, const float* __restrict__ Bws,
    __half* __restrict__ bigWT, float* __restrict__ Ubuf) {
  __shared__ __align__(16) float S[9216];
  int bi = blockIdx.x;
  int kh = bi / 5, role = bi % 5;
  int k = kh >> 2, h = kh & 3;
  int tid = threadIdx.x;
  int j = tid & 63;
  if (role < 4) {
    int r0 = role * 32;
    #pragma unroll
    for (int u = 0; u < 4; ++u)
      ((float4*)S)[u * 256 + tid] = ((const float4*)(Bws + kh * 8192))[u * 256 + tid];
    #pragma unroll
    for (int u = 0; u < 2; ++u) {
      int fi = u * 256 + tid;
      int i = fi >> 4, c4 = fi & 15;
      ((float4*)(S + 4096))[fi] =
          ((const float4*)(Wfc + (r0 + i) * 256 + h * 64))[c4];
    }
    __syncthreads();
    int ig = tid >> 6;
    int i0 = ig * 8;
    #pragma unroll
    for (int g4 = 0; g4 < 2; ++g4) {
      int ib = i0 + g4 * 4;
      float a0 = 0.f, a1 = 0.f, a2 = 0.f, a3 = 0.f;
      #pragma unroll
      for (int t4 = 0; t4 < 16; ++t4) {
        float4 f0 = *(const float4*)&S[4096 + (ib + 0) * 64 + t4 * 4];
        float4 f1 = *(const float4*)&S[4096 + (ib + 1) * 64 + t4 * 4];
        float4 f2 = *(const float4*)&S[4096 + (ib + 2) * 64 + t4 * 4];
        float4 f3 = *(const float4*)&S[4096 + (ib + 3) * 64 + t4 * 4];
        float b0 = S[(t4 * 4 + 0) * 64 + j];
        float b1 = S[(t4 * 4 + 1) * 64 + j];
        float b2 = S[(t4 * 4 + 2) * 64 + j];
        float b3 = S[(t4 * 4 + 3) * 64 + j];
        a0 += f0.x * b0 + f0.y * b1 + f0.z * b2 + f0.w * b3;
        a1 += f1.x * b0 + f1.y * b1 + f1.z * b2 + f1.w * b3;
        a2 += f2.x * b0 + f2.y * b1 + f2.z * b2 + f2.w * b3;
        a3 += f3.x * b0 + f3.y * b1 + f3.z * b2 + f3.w * b3;
      }
      // bigWT[row][col]: row = (k+1)*256 + h*64 + j, cols r0+ib..+3 (half4)
      __half hv[4] = {__float2half(a0), __float2half(a1), __float2half(a2),
                      __float2half(a3)};
      *(uint2*)&bigWT[((k + 1) * 256 + h * 64 + j) * 128 + r0 + ib] =
          *(uint2*)hv;
    }
    if (k == 0) {
      #pragma unroll
      for (int u = 0; u < 8; ++u) {
        int idx = u * 256 + tid;
        int i = idx >> 6, jj = idx & 63;
        bigWT[(h * 64 + jj) * 128 + r0 + i] = __float2half(S[4096 + idx]);
      }
    }
  } else {
    // [0:4096) B2, [4096:6144) G, [6144:7168) emb, [7168:9216) GB
    #pragma unroll
    for (int u = 0; u < 4; ++u)
      ((float4*)S)[u * 256 + tid] =
          ((const float4*)(Bws + kh * 8192 + 4096))[u * 256 + tid];
    #pragma unroll
    for (int u = 0; u < 2; ++u)
      ((float4*)(S + 4096))[u * 256 + tid] =
          ((const float4*)(G + h * 2048))[u * 256 + tid];
    ((float4*)(S + 6144))[tid] = ((const float4*)emb)[tid];
    __syncthreads();
    int wv = tid >> 6;
    #pragma unroll
    for (int rg = 0; rg < 2; ++rg) {
      int g0 = wv * 8 + rg * 4;
      float a0 = 0.f, a1 = 0.f, a2 = 0.f, a3 = 0.f;
      #pragma unroll
      for (int t4 = 0; t4 < 16; ++t4) {
        float4 f0 = *(const float4*)&S[4096 + (g0 + 0) * 64 + t4 * 4];
        float4 f1 = *(const float4*)&S[4096 + (g0 + 1) * 64 + t4 * 4];
        float4 f2 = *(const float4*)&S[4096 + (g0 + 2) * 64 + t4 * 4];
        float4 f3 = *(const float4*)&S[4096 + (g0 + 3) * 64 + t4 * 4];
        float b0 = S[(t4 * 4 + 0) * 64 + j];
        float b1 = S[(t4 * 4 + 1) * 64 + j];
        float b2 = S[(t4 * 4 + 2) * 64 + j];
        float b3 = S[(t4 * 4 + 3) * 64 + j];
        a0 += f0.x * b0 + f0.y * b1 + f0.z * b2 + f0.w * b3;
        a1 += f1.x * b0 + f1.y * b1 + f1.z * b2 + f1.w * b3;
        a2 += f2.x * b0 + f2.y * b1 + f2.z * b2 + f2.w * b3;
        a3 += f3.x * b0 + f3.y * b1 + f3.z * b2 + f3.w * b3;
      }
      S[7168 + (g0 + 0) * 64 + j] = a0;
      S[7168 + (g0 + 1) * 64 + j] = a1;
      S[7168 + (g0 + 2) * 64 + j] = a2;
      S[7168 + (g0 + 3) * 64 + j] = a3;
    }
    __syncthreads();
    #pragma unroll
    for (int rg = 0; rg < 2; ++rg) {
      int e0 = wv * 8 + rg * 4;
      float a0 = 0.f, a1 = 0.f, a2 = 0.f, a3 = 0.f;
      #pragma unroll
      for (int t4 = 0; t4 < 8; ++t4) {
        float4 f0 = *(const float4*)&S[6144 + (e0 + 0) * 32 + t4 * 4];
        float4 f1 = *(const float4*)&S[6144 + (e0 + 1) * 32 + t4 * 4];
        float4 f2 = *(const float4*)&S[6144 + (e0 + 2) * 32 + t4 * 4];
        float4 f3 = *(const float4*)&S[6144 + (e0 + 3) * 32 + t4 * 4];
        float b0 = S[7168 + (t4 * 4 + 0) * 64 + j];
        float b1 = S[7168 + (t4 * 4 + 1) * 64 + j];
        float b2 = S[7168 + (t4 * 4 + 2) * 64 + j];
        float b3 = S[7168 + (t4 * 4 + 3) * 64 + j];
        a0 += f0.x * b0 + f0.y * b1 + f0.z * b2 + f0.w * b3;
        a1 += f1.x * b0 + f1.y * b1 + f1.z * b2 + f1.w * b3;
        a2 += f2.x * b0 + f2.y * b1 + f2.z * b2 + f2.w * b3;
        a3 += f3.x * b0 + f3.y * b1 + f3.z * b2 + f3.w * b3;
      }
      Ubuf[k * 8192 + h * 2048 + (e0 + 0) * 64 + j] = a0;
      Ubuf[k * 8192 + h * 2048 + (e0 + 1) * 64 + j] = a1;
      Ubuf[k * 8192 + h * 2048 + (e0 + 2) * 64 + j] = a2;
      Ubuf[k * 8192 + h * 2048 + (e0 + 3) * 64 + j] = a3;
    }
  }
}

// ---------------------------------------------------------------------------
// feat fp32 -> fp16
// ---------------------------------------------------------------------------
__global__ __launch_bounds__(256) void cvt_kernel(const float* __restrict__ feat,
                                                  __half* __restrict__ feat16) {
  int t = blockIdx.x * 256 + threadIdx.x;
  if (t < N_NODES * 128 / 4) {
    float4 v = *(const float4*)(feat + t * 4);
    union { uint2 u; __half2 h[2]; } st;
    st.h[0] = __floats2half2_rn(v.x, v.y);
    st.h[1] = __floats2half2_rn(v.z, v.w);
    *(uint2*)&feat16[t * 4] = st.u;
  }
}

// ---------------------------------------------------------------------------
// K1: qall(fp16) = feat16 (10000x128) @ bigWT^T via MFMA 16x16x32 f16.
// Block 256 = 4 waves; wave = 16-row m-strip, 64 n-cols (4 subtiles).
// A[m=l&15][k=(l>>4)*8+j]; B[k=(l>>4)*8+j][n=l&15] from bigWT[n][k];
// D: col=l&15, row=(l>>4)*4+reg.
// ---------------------------------------------------------------------------
__global__ __launch_bounds__(256) void gemm_kernel(
    const __half* __restrict__ feat16, const __half* __restrict__ bigWT,
    __half* __restrict__ qall) {
  int tid = threadIdx.x;
  int wv = tid >> 6, l = tid & 63;
  int m0 = blockIdx.x * 64 + wv * 16;
  int n0 = blockIdx.y * 64;
  int lm = l & 15, lk = (l >> 4) * 8;
  int arow = m0 + lm;
  if (arow >= N_NODES) arow = N_NODES - 1;
  const _Float16* fp = (const _Float16*)feat16 + arow * 128 + lk;
  const _Float16* bp = (const _Float16*)bigWT + lk;
  floatx4 acc[4];
  #pragma unroll
  for (int nt = 0; nt < 4; ++nt) acc[nt] = (floatx4){0.f, 0.f, 0.f, 0.f};
  #pragma unroll
  for (int kt = 0; kt < 4; ++kt) {
    half8 a = *(const half8*)(fp + kt * 32);
    #pragma unroll
    for (int nt = 0; nt < 4; ++nt) {
      half8 b = *(const half8*)(bp + (n0 + nt * 16 + lm) * 128 + kt * 32);
      acc[nt] = __builtin_amdgcn_mfma_f32_16x16x32_f16(a, b, acc[nt], 0, 0, 0);
    }
  }
  int mrow = m0 + (l >> 4) * 4;
  #pragma unroll
  for (int nt = 0; nt < 4; ++nt) {
    #pragma unroll
    for (int r = 0; r < 4; ++r) {
      int m = mrow + r;
      if (m < N_NODES)
        qall[m * QREC + n0 + nt * 16 + lm] = __float2half(acc[nt][r]);
    }
  }
}

// ---------------------------------------------------------------------------
// CSR build
// ---------------------------------------------------------------------------
__global__ __launch_bounds__(256) void count_kernel(const int* __restrict__ dst,
                                                    int* __restrict__ counts) {
  int e = blockIdx.x * 256 + threadIdx.x;
  if (e < E_EDGES) atomicAdd(&counts[dst[e]], 1);
}

__global__ __launch_bounds__(1024) void scan_kernel(const int* __restrict__ counts,
                                                    int* __restrict__ starts,
                                                    int* __restrict__ cursor) {
  __shared__ int lds[1024];
  int tid = threadIdx.x;
  int base = tid * 10;
  int loc[10];
  int s = 0;
  #pragma unroll
  for (int u = 0; u < 10; ++u) {
    int i = base + u;
    int v = (i < N_NODES) ? counts[i] : 0;
    loc[u] = s;
    s += v;
  }
  lds[tid] = s;
  __syncthreads();
  int inc = s;
  for (int off = 1; off < 1024; off <<= 1) {
    int y = (tid >= off) ? lds[tid - off] : 0;
    __syncthreads();
    inc += y;
    lds[tid] = inc;
    __syncthreads();
  }
  int excl = inc - s;
  #pragma unroll
  for (int u = 0; u < 10; ++u) {
    int i = base + u;
    if (i < N_NODES) {
      int v = excl + loc[u];
      starts[i] = v;
      cursor[i] = v;
    }
  }
  if (tid == 1023) starts[N_NODES] = inc;
}

__global__ __launch_bounds__(256) void fill_kernel(const int* __restrict__ dst,
                                                   int* __restrict__ cursor,
                                                   int* __restrict__ elist) {
  int e = blockIdx.x * 256 + threadIdx.x;
  if (e < E_EDGES) {
    int p = atomicAdd(&cursor[dst[e]], 1);
    elist[p] = e;
  }
}

// ---------------------------------------------------------------------------
// K3: FUSED score + softmax + aggregate (max-free; |score| <= ~15).
// Block = dst node; 4 waves stride edges; lane: h=lane>>4, c=lane&15.
// DPP row_ror butterfly for the 16-lane dot reduce (head group == DPP row).
// ---------------------------------------------------------------------------
__device__ __forceinline__ int didx(const float* __restrict__ bnd2, float d) {
  int g = (int)(d * 10.0f);
  g = (g < 0) ? 0 : ((g > 31) ? 31 : g);
  g += (bnd2[g + 1] < d) ? 1 : 0;
  g -= (bnd2[g] >= d) ? 1 : 0;
  return g;
}

__device__ __forceinline__ float fast_tanh(float z) {
  float a = fabsf(z);
  float p = __expf(2.0f * a);
  float r = 1.0f - 2.0f / (p + 1.0f);
  return copysignf(r, z);
}

__device__ __forceinline__ float dpp_row_sum16(float v) {
  int x;
  x = __builtin_amdgcn_update_dpp(0, __float_as_int(v), 0x128, 0xf, 0xf, true);
  v += __int_as_float(x);  // + lane^... rotate 8
  x = __builtin_amdgcn_update_dpp(0, __float_as_int(v), 0x124, 0xf, 0xf, true);
  v += __int_as_float(x);  // rotate 4
  x = __builtin_amdgcn_update_dpp(0, __float_as_int(v), 0x122, 0xf, 0xf, true);
  v += __int_as_float(x);  // rotate 2
  x = __builtin_amdgcn_update_dpp(0, __float_as_int(v), 0x121, 0xf, 0xf, true);
  v += __int_as_float(x);  // rotate 1
  return v;
}

__device__ __forceinline__ float4 h4_to_f4(uint2 u) {
  union { uint2 ui; __half2 h[2]; } c;
  c.ui = u;
  float2 a = __half22float2(c.h[0]);
  float2 b = __half22float2(c.h[1]);
  return make_float4(a.x, a.y, b.x, b.y);
}

__device__ __forceinline__ void fma4(float4& a, float s, const float4& b) {
  a.x += s * b.x; a.y += s * b.y; a.z += s * b.z; a.w += s * b.w;
}

__global__ __launch_bounds__(256) void fused_kernel(
    const int* __restrict__ starts, const int* __restrict__ elist,
    const int* __restrict__ src, const int* __restrict__ inter,
    const float* __restrict__ pos, const float* __restrict__ boundaries,
    const __half* __restrict__ qall, const float* __restrict__ U,
    const float* __restrict__ aout, float* __restrict__ out) {
  __shared__ float bnd2[33];
  __shared__ float4 sm_num[4][64];
  __shared__ float sm_den[4][4];
  __shared__ float sm_red[4][64];
  int tid = threadIdx.x;
  if (tid < NBOUND) bnd2[tid + 1] = boundaries[tid];
  if (tid == NBOUND) { bnd2[0] = -INFINITY; bnd2[32] = INFINITY; }
  __syncthreads();
  int w = tid >> 6;
  int lane = tid & 63;
  int h = lane >> 4;
  int c = lane & 15;
  int n = blockIdx.x;
  int b = starts[n], e_end = starts[n + 1];
  float tx = pos[n * 3], ty = pos[n * 3 + 1], tz = pos[n * 3 + 2];
  const float4 q3f = h4_to_f4(*(const uint2*)(qall + n * QREC + 768 + h * 64 + c * 4));
  const float4 a4 = *((const float4*)(aout + h * 64) + c);
  float4 acc = make_float4(0.f, 0.f, 0.f, 0.f);
  float den = 0.f;
  int i = b + w;
  int s = 0, it = 0;
  float sx = 0.f, sy = 0.f, sz = 0.f, ix = 0.f, iy = 0.f, iz = 0.f;
  uint2 rA = {0, 0}, rB = {0, 0}, rH = {0, 0};
  if (i < e_end) {
    int e = elist[i];
    s = src[e];
    it = inter[e * H + h];
    sx = pos[s * 3]; sy = pos[s * 3 + 1]; sz = pos[s * 3 + 2];
    ix = pos[it * 3]; iy = pos[it * 3 + 1]; iz = pos[it * 3 + 2];
    rA = *(const uint2*)(qall + s * QREC + 256 + h * 64 + c * 4);
    rB = *(const uint2*)(qall + it * QREC + 512 + h * 64 + c * 4);
    rH = *(const uint2*)(qall + s * QREC + h * 64 + c * 4);
  }
  while (i < e_end) {
    int inext = i + 4;
    int sn = 0, itn = 0;
    float sxn = 0.f, syn = 0.f, szn = 0.f, ixn = 0.f, iyn = 0.f, izn = 0.f;
    uint2 rAn = {0, 0}, rBn = {0, 0}, rHn = {0, 0};
    if (inext < e_end) {
      int en = elist[inext];
      sn = src[en];
      itn = inter[en * H + h];
      sxn = pos[sn * 3]; syn = pos[sn * 3 + 1]; szn = pos[sn * 3 + 2];
      ixn = pos[itn * 3]; iyn = pos[itn * 3 + 1]; izn = pos[itn * 3 + 2];
      rAn = *(const uint2*)(qall + sn * QREC + 256 + h * 64 + c * 4);
      rBn = *(const uint2*)(qall + itn * QREC + 512 + h * 64 + c * 4);
      rHn = *(const uint2*)(qall + sn * QREC + h * 64 + c * 4);
    }
    float dx = tx - sx, dy = ty - sy, dz = tz - sz;
    float dist1 = sqrtf(dx * dx + dy * dy + dz * dz);
    float ax = tx - ix, ay = ty - iy, az = tz - iz;
    float dist2 = sqrtf(ax * ax + ay * ay + az * az);
    float bx = sx - ix, by = sy - iy, bz = sz - iz;
    float dist_ = sqrtf(bx * bx + by * by + bz * bz);
    int idx1 = didx(bnd2, dist1);
    int idx2 = didx(bnd2, dist2);
    int idx_ = didx(bnd2, dist_);
    const float4 X = *((const float4*)(U + (h * 32 + idx1) * 64) + c);
    const float4 Y = *((const float4*)(U + 8192 + (h * 32 + idx2) * 64) + c);
    const float4 Z = *((const float4*)(U + 16384 + (h * 32 + idx_) * 64) + c);
    const float4 A = h4_to_f4(rA);
    const float4 B = h4_to_f4(rB);
    const float4 hb = h4_to_f4(rH);
    float t0 = fast_tanh(A.x + B.x + q3f.x + X.x + Y.x + Z.x);
    float t1 = fast_tanh(A.y + B.y + q3f.y + X.y + Y.y + Z.y);
    float t2 = fast_tanh(A.z + B.z + q3f.z + X.z + Y.z + Z.z);
    float t3 = fast_tanh(A.w + B.w + q3f.w + X.w + Y.w + Z.w);
    float v = t0 * a4.x + t1 * a4.y + t2 * a4.z + t3 * a4.w;
    v = dpp_row_sum16(v);
    float ex = __expf(v);
    den += ex;
    fma4(acc, ex, hb);
    i = inext;
    s = sn; it = itn;
    sx = sxn; sy = syn; sz = szn; ix = ixn; iy = iyn; iz = izn;
    rA = rAn; rB = rBn; rH = rHn;
  }
  sm_num[w][lane] = acc;
  if (c == 0) sm_den[w][h] = den;
  __syncthreads();
  int hh = tid >> 6, d = tid & 63;
  float dsum = sm_den[0][hh] + sm_den[1][hh] + sm_den[2][hh] + sm_den[3][hh];
  float v = 0.f;
  #pragma unroll
  for (int wv = 0; wv < 4; ++wv)
    v += ((const float*)&sm_num[wv][hh * 16 + (d >> 2)])[d & 3];
  sm_red[hh][d] = (e_end > b) ? (v / dsum) : 0.f;
  __syncthreads();
  if (tid < 64) {
    out[n * 64 + tid] = 0.25f * (sm_red[0][tid] + sm_red[1][tid] +
                                 sm_red[2][tid] + sm_red[3][tid]);
  }
}

// ---------------------------------------------------------------------------
extern "C" void kernel_launch(void* const* d_in, const int* in_sizes, int n_in,
                              void* d_out, int out_size, void* d_ws,
                              size_t ws_size, hipStream_t stream) {
  const float* feat = (const float*)d_in[0];
  const float* loc = (const float*)d_in[1];
  const int* src = (const int*)d_in[2];
  const int* dst = (const int*)d_in[3];
  const int* inter = (const int*)d_in[4];
  const float* Wfc = (const float*)d_in[5];
  const float* emb = (const float*)d_in[6];
  const float* G = (const float*)d_in[7];
  const float* fc1 = (const float*)d_in[8];
  const float* fc2 = (const float*)d_in[9];
  const float* fc3 = (const float*)d_in[10];
  const float* fcc = (const float*)d_in[11];
  const float* aout = (const float*)d_in[12];
  const float* bnd = (const float*)d_in[13];
  float* out = (float*)d_out;

  __half* qall = (__half*)d_ws;                    // N*1024 halfs
  __half* feat16 = qall + N_NODES * QREC;          // N*128 halfs
  __half* bigWT = feat16 + N_NODES * 128;          // 1024*128 halfs
  float* Bws = (float*)(bigWT + 1024 * 128);       // 12*8192 f32
  float* Ubuf = Bws + 12 * 8192;                   // 3*4*2048 f32
  int* counts = (int*)(Ubuf + 3 * H * 2048);       // N
  int* starts = counts + N_NODES;                  // N+1
  int* cursor = starts + N_NODES + 1;              // N
  int* elist = cursor + N_NODES;                   // E

  hipMemsetAsync(counts, 0, N_NODES * sizeof(int), stream);
  count_kernel<<<(E_EDGES + 255) / 256, 256, 0, stream>>>(dst, counts);
  cvt_kernel<<<(N_NODES * 128 / 4 + 255) / 256, 256, 0, stream>>>(feat, feat16);
  pre1_kernel<<<12, 256, 0, stream>>>(fc1, fc2, fc3, fcc, Bws);
  pre2_kernel<<<60, 256, 0, stream>>>(Wfc, G, emb, Bws, bigWT, Ubuf);
  scan_kernel<<<1, 1024, 0, stream>>>(counts, starts, cursor);
  fill_kernel<<<(E_EDGES + 255) / 256, 256, 0, stream>>>(dst, cursor, elist);
  dim3 ggrid((N_NODES + 63) / 64, 16);
  gemm_kernel<<<ggrid, 256, 0, stream>>>(feat16, bigWT, qall);
  fused_kernel<<<N_NODES, 256, 0, stream>>>(starts, elist, src, inter, loc,
                                            bnd, qall, Ubuf, aout, out);
}